// Round 3
// baseline (271.792 us; speedup 1.0000x reference)
//
#include <hip/hip_runtime.h>

// Fused SSIM, B=64, C=1, 512x512 fp32, 11x11 separable Gaussian.
// Phase 1: vertical conv from GLOBAL via register strips (interior blocks take
//          an unchecked fast path). Results (5 ch) -> LDS, column anchor = +5.
// Phase 2: horizontal conv from LDS via 5 aligned float4 reads per channel
//          (tap window c0..c0+17 inside words c0..c0+19) + SSIM + reduce.

#define IMG 512
#define TW 64            // output tile width
#define TH 32            // output tile height
#define PADC 76          // stored v-columns: image cols x0-5 .. x0+70 (74 used + 2 pad)
#define SEGROWS 8        // output rows per phase-1 segment
#define INROWS 18        // input rows per segment (8 + 10 halo)
#define NTHREADS 320

__global__ __launch_bounds__(NTHREADS, 3) void ssim_fused(
    const float* __restrict__ x, const float* __restrict__ y,
    const float* __restrict__ win, float* __restrict__ partial)
{
    __shared__ __align__(16) float v[5][TH][PADC];   // 48640 B
    __shared__ float sg[11];
    __shared__ float redbuf[5];

    const int tid = threadIdx.x;

    // 1D kernel g[i] = row sums of the 2D window (exact since sum(g)==1).
    if (tid < 11) {
        float s = 0.f;
        #pragma unroll
        for (int j = 0; j < 11; ++j) s += win[tid * 11 + j];
        sg[tid] = s;
    }

    const int x0 = blockIdx.x * TW;
    const int y0 = blockIdx.y * TH;
    const size_t img_off = (size_t)blockIdx.z * (IMG * IMG);
    const float* __restrict__ xb = x + img_off;
    const float* __restrict__ yb = y + img_off;

    // ---------------- Phase 1: vertical conv (global -> LDS) ----------------
    const int s  = tid / 80;          // segment 0..3
    const int c  = tid - s * 80;      // raw column lane 0..79
    const int r0 = s * SEGROWS;       // first output row of this segment
    const int gx = x0 + c - 5;        // global column (v col anchor = +5)
    const int cw = (c < PADC) ? c : (PADC - 1);  // junk lanes write pad col 75

    // Interior: all 18 rows and all 80 lane-columns in-bounds.
    const bool interior = (x0 > 0) && (x0 < 448) && (y0 > 0) && (y0 < 480);

    float vx[INROWS], vy[INROWS];
    if (interior) {
        const float* __restrict__ px = xb + (y0 + r0 - 5) * IMG + gx;
        const float* __restrict__ py = yb + (y0 + r0 - 5) * IMG + gx;
        #pragma unroll
        for (int j = 0; j < INROWS; ++j) {
            vx[j] = px[j * IMG];
            vy[j] = py[j * IMG];
        }
    } else {
        const bool cok = (gx >= 0) && (gx < IMG);
        #pragma unroll
        for (int j = 0; j < INROWS; ++j) {
            int gy = y0 + r0 - 5 + j;
            bool ok = cok && (gy >= 0) && (gy < IMG);
            int o = ok ? (gy * IMG + gx) : 0;
            float a = xb[o];
            float b = yb[o];
            vx[j] = ok ? a : 0.f;
            vy[j] = ok ? b : 0.f;
        }
    }

    __syncthreads();   // sg visible
    float gk[11];
    #pragma unroll
    for (int k = 0; k < 11; ++k) gk[k] = sg[k];

    // channels 0,1: x, y
    #pragma unroll
    for (int i = 0; i < SEGROWS; ++i) {
        float a = 0.f, b = 0.f;
        #pragma unroll
        for (int k = 0; k < 11; ++k) { a += gk[k] * vx[i + k]; b += gk[k] * vy[i + k]; }
        v[0][r0 + i][cw] = a;
        v[1][r0 + i][cw] = b;
    }
    // channel 2: x*x
    {
        float t[INROWS];
        #pragma unroll
        for (int j = 0; j < INROWS; ++j) t[j] = vx[j] * vx[j];
        #pragma unroll
        for (int i = 0; i < SEGROWS; ++i) {
            float a = 0.f;
            #pragma unroll
            for (int k = 0; k < 11; ++k) a += gk[k] * t[i + k];
            v[2][r0 + i][cw] = a;
        }
    }
    // channel 3: y*y
    {
        float t[INROWS];
        #pragma unroll
        for (int j = 0; j < INROWS; ++j) t[j] = vy[j] * vy[j];
        #pragma unroll
        for (int i = 0; i < SEGROWS; ++i) {
            float a = 0.f;
            #pragma unroll
            for (int k = 0; k < 11; ++k) a += gk[k] * t[i + k];
            v[3][r0 + i][cw] = a;
        }
    }
    // channel 4: x*y
    {
        float t[INROWS];
        #pragma unroll
        for (int j = 0; j < INROWS; ++j) t[j] = vx[j] * vy[j];
        #pragma unroll
        for (int i = 0; i < SEGROWS; ++i) {
            float a = 0.f;
            #pragma unroll
            for (int k = 0; k < 11; ++k) a += gk[k] * t[i + k];
            v[4][r0 + i][cw] = a;
        }
    }

    __syncthreads();

    // ---------------- Phase 2: horizontal conv + SSIM ----------------
    const float C1 = 1.0e-4f;
    const float C2 = 9.0e-4f;
    float acc = 0.f;

    if (tid < 256) {
        const int rr = tid >> 3;          // row 0..31
        const int c0 = (tid & 7) * 8;     // output col base 0..56 (step 8)

        float mx[8], my[8], exx[8], eyy[8], exy[8];

        #pragma unroll
        for (int ch = 0; ch < 5; ++ch) {
            float t[20];
            const float4* vp = (const float4*)&v[ch][rr][c0];
            #pragma unroll
            for (int q = 0; q < 5; ++q) {
                float4 f = vp[q];
                t[4*q + 0] = f.x; t[4*q + 1] = f.y; t[4*q + 2] = f.z; t[4*q + 3] = f.w;
            }
            // out col c0+i taps image cols (c0+i-5..c0+i+5) -> words c0+i .. c0+i+10
            #pragma unroll
            for (int i = 0; i < 8; ++i) {
                float a = 0.f;
                #pragma unroll
                for (int k = 0; k < 11; ++k) a += gk[k] * t[i + k];
                if (ch == 0) mx[i] = a;
                else if (ch == 1) my[i] = a;
                else if (ch == 2) exx[i] = a;
                else if (ch == 3) eyy[i] = a;
                else exy[i] = a;
            }
        }

        #pragma unroll
        for (int i = 0; i < 8; ++i) {
            float mxv = mx[i], myv = my[i];
            float mxx = mxv * mxv, myy = myv * myv, mxy = mxv * myv;
            float sxx = exx[i] - mxx;
            float syy = eyy[i] - myy;
            float sxy = exy[i] - mxy;
            float num = (2.f * mxy + C1) * (2.f * sxy + C2);
            float den = (mxx + myy + C1) * (sxx + syy + C2);
            acc += num * __builtin_amdgcn_rcpf(den);
        }
    }

    // ---------------- Phase 3: block reduction ----------------
    #pragma unroll
    for (int off = 32; off > 0; off >>= 1) acc += __shfl_down(acc, off, 64);
    int wid = tid >> 6, lane = tid & 63;
    if (lane == 0) redbuf[wid] = acc;
    __syncthreads();
    if (tid == 0) {
        float ssum = redbuf[0] + redbuf[1] + redbuf[2] + redbuf[3] + redbuf[4];
        partial[((size_t)blockIdx.z * gridDim.y + blockIdx.y) * gridDim.x + blockIdx.x] = ssum;
    }
}

__global__ __launch_bounds__(1024) void ssim_finalize(
    const float* __restrict__ partial, int n, float* __restrict__ out)
{
    __shared__ double red[16];
    double acc = 0.0;
    for (int i = threadIdx.x; i < n; i += 1024) acc += (double)partial[i];
    #pragma unroll
    for (int off = 32; off > 0; off >>= 1) acc += __shfl_down(acc, off, 64);
    int wid = threadIdx.x >> 6, lane = threadIdx.x & 63;
    if (lane == 0) red[wid] = acc;
    __syncthreads();
    if (threadIdx.x == 0) {
        double ssum = 0.0;
        #pragma unroll
        for (int w = 0; w < 16; ++w) ssum += red[w];
        out[0] = (float)(ssum / (64.0 * 512.0 * 512.0));
    }
}

extern "C" void kernel_launch(void* const* d_in, const int* in_sizes, int n_in,
                              void* d_out, int out_size, void* d_ws, size_t ws_size,
                              hipStream_t stream) {
    (void)in_sizes; (void)n_in; (void)out_size; (void)ws_size;
    const float* x   = (const float*)d_in[0];
    const float* y   = (const float*)d_in[1];
    const float* win = (const float*)d_in[2];
    float* out = (float*)d_out;
    float* partial = (float*)d_ws;     // 8192 floats = 32 KB

    dim3 grid(IMG / TW, IMG / TH, 64); // 8 x 16 x 64 = 8192 blocks
    ssim_fused<<<grid, NTHREADS, 0, stream>>>(x, y, win, partial);
    ssim_finalize<<<1, 1024, 0, stream>>>(partial, 8192, out);
}

// Round 4
// 255.835 us; speedup vs baseline: 1.0624x; 1.0624x over previous
//
#include <hip/hip_runtime.h>

// Fused SSIM, B=64, C=1, 512x512 fp32, 11x11 separable Gaussian.
// R4: packed-fp32 (v_pk_fma_f32) in both conv passes.
// Phase 1: lane = column-pair x 4 output rows; vertical conv packed over cols;
//          results transposed to row-pair-interleaved LDS (b128 writes).
// Phase 2: lane = 4 cols x 1 row-pair; horizontal conv packed over rows
//          (taps are contiguous f32x2 in LDS, aligned b128 reads); SSIM + reduce.

#define IMG 512
#define TW 64
#define TH 32
#define SCN 80           // stored cols 0..79; image col = x0 + sc - 8
#define SP 82            // f32x2 stride per row-pair (pad 2)
#define NRP 16           // row pairs (32 rows)
#define SEGROWS 4        // output rows per phase-1 segment
#define INROWS 14        // input rows per segment (4 + 10 halo)
#define NTHREADS 320

typedef __attribute__((ext_vector_type(2))) float f32x2;

__device__ __forceinline__ f32x2 pk_fma(f32x2 a, f32x2 b, f32x2 c) {
    f32x2 d;
    asm("v_pk_fma_f32 %0, %1, %2, %3" : "=v"(d) : "v"(a), "v"(b), "v"(c));
    return d;
}
__device__ __forceinline__ f32x2 pk_mul(f32x2 a, f32x2 b) {
    f32x2 d;
    asm("v_pk_mul_f32 %0, %1, %2" : "=v"(d) : "v"(a), "v"(b));
    return d;
}

__global__ __launch_bounds__(NTHREADS, 4) void ssim_fused(
    const float* __restrict__ x, const float* __restrict__ y,
    const float* __restrict__ win, float* __restrict__ partial)
{
    __shared__ __align__(16) f32x2 v2[5][NRP][SP];   // 5*16*82*8 = 52480 B
    __shared__ float sg[11];
    __shared__ float redbuf[5];

    const int tid = threadIdx.x;

    // 1D kernel g[i] = row sums of the 2D window (exact since sum(g)==1).
    if (tid < 11) {
        float s = 0.f;
        #pragma unroll
        for (int j = 0; j < 11; ++j) s += win[tid * 11 + j];
        sg[tid] = s;
    }

    const int x0 = blockIdx.x * TW;
    const int y0 = blockIdx.y * TH;
    const size_t img_off = (size_t)blockIdx.z * (IMG * IMG);
    const f32x2* __restrict__ xb2 = (const f32x2*)(x + img_off);
    const f32x2* __restrict__ yb2 = (const f32x2*)(y + img_off);

    // ---------------- Phase 1: vertical conv (global -> LDS) ----------------
    const int s  = tid / 40;          // segment 0..7 (4 output rows each)
    const int u  = tid - s * 40;      // column-pair group 0..39 (sc = 2u, 2u+1)
    const int r0 = s * SEGROWS;
    const int gx = x0 + 2 * u - 8;    // even; both cols of the pair share bounds
    const bool cok = (gx >= 0) && (gx < IMG);
    const f32x2 z2 = (f32x2)(0.f);

    f32x2 vx[INROWS], vy[INROWS];
    #pragma unroll
    for (int j = 0; j < INROWS; ++j) {
        int gy = y0 + r0 - 5 + j;
        bool ok = cok && (gy >= 0) && (gy < IMG);
        int o = ok ? (gy * (IMG / 2) + (gx >> 1)) : 0;
        f32x2 a = xb2[o];
        f32x2 b = yb2[o];
        vx[j] = ok ? a : z2;
        vy[j] = ok ? b : z2;
    }

    __syncthreads();   // sg visible
    f32x2 g2[11];
    #pragma unroll
    for (int k = 0; k < 11; ++k) { float gv = sg[k]; g2[k][0] = gv; g2[k][1] = gv; }

    // Write helper: results a[r] (r=0..3, packed over col pair) -> interleaved
    // layout: v2[ch][rowpair][sc] = (rowEven, rowOdd). 16B-aligned quads.
    #define STORE_CH(CH, A)                                              \
        {                                                                \
            _Pragma("unroll")                                            \
            for (int rl = 0; rl < 2; ++rl) {                             \
                float* w = (float*)&v2[CH][2 * s + rl][2 * u];           \
                w[0] = A[2 * rl][0];                                     \
                w[1] = A[2 * rl + 1][0];                                 \
                w[2] = A[2 * rl][1];                                     \
                w[3] = A[2 * rl + 1][1];                                 \
            }                                                            \
        }

    // channels 0 (x), 1 (y)
    {
        f32x2 a0[SEGROWS], a1[SEGROWS];
        #pragma unroll
        for (int r = 0; r < SEGROWS; ++r) {
            f32x2 a = z2, b = z2;
            #pragma unroll
            for (int k = 0; k < 11; ++k) {
                a = pk_fma(g2[k], vx[r + k], a);
                b = pk_fma(g2[k], vy[r + k], b);
            }
            a0[r] = a; a1[r] = b;
        }
        STORE_CH(0, a0)
        STORE_CH(1, a1)
    }
    // channel 2: x*x
    {
        f32x2 t[INROWS], a0[SEGROWS];
        #pragma unroll
        for (int j = 0; j < INROWS; ++j) t[j] = pk_mul(vx[j], vx[j]);
        #pragma unroll
        for (int r = 0; r < SEGROWS; ++r) {
            f32x2 a = z2;
            #pragma unroll
            for (int k = 0; k < 11; ++k) a = pk_fma(g2[k], t[r + k], a);
            a0[r] = a;
        }
        STORE_CH(2, a0)
    }
    // channel 3: y*y
    {
        f32x2 t[INROWS], a0[SEGROWS];
        #pragma unroll
        for (int j = 0; j < INROWS; ++j) t[j] = pk_mul(vy[j], vy[j]);
        #pragma unroll
        for (int r = 0; r < SEGROWS; ++r) {
            f32x2 a = z2;
            #pragma unroll
            for (int k = 0; k < 11; ++k) a = pk_fma(g2[k], t[r + k], a);
            a0[r] = a;
        }
        STORE_CH(3, a0)
    }
    // channel 4: x*y
    {
        f32x2 t[INROWS], a0[SEGROWS];
        #pragma unroll
        for (int j = 0; j < INROWS; ++j) t[j] = pk_mul(vx[j], vy[j]);
        #pragma unroll
        for (int r = 0; r < SEGROWS; ++r) {
            f32x2 a = z2;
            #pragma unroll
            for (int k = 0; k < 11; ++k) a = pk_fma(g2[k], t[r + k], a);
            a0[r] = a;
        }
        STORE_CH(4, a0)
    }

    __syncthreads();

    // ---------------- Phase 2: horizontal conv + SSIM ----------------
    const float C1 = 1.0e-4f;
    const float C2 = 9.0e-4f;
    float acc = 0.f;

    if (tid < 256) {
        const int rp = tid >> 4;          // row pair 0..15
        const int cg = tid & 15;          // col group 0..15
        const int c0 = 4 * cg;            // output cols c0..c0+3
        // out col c taps sc = c+3 .. c+13 (sc holds image col x0+sc-8).
        // Read sc_base = c0+2 .. c0+17 (16 f32x2, 16B-aligned), t2 idx j = sc-sc_base.
        f32x2 res[5][4];

        #pragma unroll
        for (int ch = 0; ch < 5; ++ch) {
            f32x2 t2[16];
            const float4* vp4 = (const float4*)&v2[ch][rp][c0 + 2];
            #pragma unroll
            for (int q = 0; q < 8; ++q) {
                float4 f = vp4[q];
                t2[2 * q][0] = f.x;  t2[2 * q][1] = f.y;
                t2[2 * q + 1][0] = f.z;  t2[2 * q + 1][1] = f.w;
            }
            #pragma unroll
            for (int c = 0; c < 4; ++c) {
                f32x2 a = (f32x2)(0.f);
                #pragma unroll
                for (int k = 0; k < 11; ++k) a = pk_fma(g2[k], t2[c + 1 + k], a);
                res[ch][c] = a;
            }
        }

        #pragma unroll
        for (int c = 0; c < 4; ++c) {
            #pragma unroll
            for (int p = 0; p < 2; ++p) {
                float mxv = res[0][c][p], myv = res[1][c][p];
                float exx = res[2][c][p], eyy = res[3][c][p], exy = res[4][c][p];
                float mxx = mxv * mxv, myy = myv * myv, mxy = mxv * myv;
                float sxx = exx - mxx;
                float syy = eyy - myy;
                float sxy = exy - mxy;
                float num = (2.f * mxy + C1) * (2.f * sxy + C2);
                float den = (mxx + myy + C1) * (sxx + syy + C2);
                acc += num * __builtin_amdgcn_rcpf(den);
            }
        }
    }

    // ---------------- Phase 3: block reduction ----------------
    #pragma unroll
    for (int off = 32; off > 0; off >>= 1) acc += __shfl_down(acc, off, 64);
    int wid = tid >> 6, lane = tid & 63;
    if (lane == 0) redbuf[wid] = acc;
    __syncthreads();
    if (tid == 0) {
        float ssum = redbuf[0] + redbuf[1] + redbuf[2] + redbuf[3] + redbuf[4];
        partial[((size_t)blockIdx.z * gridDim.y + blockIdx.y) * gridDim.x + blockIdx.x] = ssum;
    }
}

__global__ __launch_bounds__(256) void ssim_finalize(
    const float* __restrict__ partial, int n, float* __restrict__ out)
{
    __shared__ double red[4];
    double acc = 0.0;
    for (int i = threadIdx.x; i < n; i += 256) acc += (double)partial[i];
    #pragma unroll
    for (int off = 32; off > 0; off >>= 1) acc += __shfl_down(acc, off, 64);
    int wid = threadIdx.x >> 6, lane = threadIdx.x & 63;
    if (lane == 0) red[wid] = acc;
    __syncthreads();
    if (threadIdx.x == 0) {
        double s = red[0] + red[1] + red[2] + red[3];
        out[0] = (float)(s / (64.0 * 512.0 * 512.0));
    }
}

extern "C" void kernel_launch(void* const* d_in, const int* in_sizes, int n_in,
                              void* d_out, int out_size, void* d_ws, size_t ws_size,
                              hipStream_t stream) {
    (void)in_sizes; (void)n_in; (void)out_size; (void)ws_size;
    const float* x   = (const float*)d_in[0];
    const float* y   = (const float*)d_in[1];
    const float* win = (const float*)d_in[2];
    float* out = (float*)d_out;
    float* partial = (float*)d_ws;     // 8192 floats = 32 KB

    dim3 grid(IMG / TW, IMG / TH, 64); // 8 x 16 x 64 = 8192 blocks
    ssim_fused<<<grid, NTHREADS, 0, stream>>>(x, y, win, partial);
    ssim_finalize<<<1, 256, 0, stream>>>(partial, 8192, out);
}

// Round 5
// 213.676 us; speedup vs baseline: 1.2720x; 1.1973x over previous
//
#include <hip/hip_runtime.h>

// Fused SSIM, B=64, C=1, 512x512 fp32, 11x11 separable Gaussian.
// R5: R2 skeleton (proven banking/scheduling) + packed fp32 via CHANNEL-PAIR
// packing: planes (x,y) and (xx,yy) stored as f32x2, xy scalar. pk_fma taps
// are whole f32x2 elements -> no packed-operand shifts anywhere.
// Phase 1: vertical conv from global (per-lane column, R2 bounds code).
// Phase 2: horizontal conv from LDS (aligned float4 runs) + SSIM + reduce.

#define IMG 512
#define TW 64
#define TH 32
#define SAB 78           // f32x2 stride, ab/qq planes (156 words; 156%32=28 -> 8 read start-banks)
#define SXY 84           // float stride, xy plane (336 B, 16B aligned; 84%32=20 -> 8 start-banks)
#define NTHREADS 320

typedef __attribute__((ext_vector_type(2))) float f32x2;

static __device__ __forceinline__ f32x2 pk_fma(f32x2 a, f32x2 b, f32x2 c) {
    f32x2 d;
    asm("v_pk_fma_f32 %0, %1, %2, %3" : "=v"(d) : "v"(a), "v"(b), "v"(c));
    return d;
}
static __device__ __forceinline__ f32x2 pk_mul(f32x2 a, f32x2 b) {
    f32x2 d;
    asm("v_pk_mul_f32 %0, %1, %2" : "=v"(d) : "v"(a), "v"(b));
    return d;
}

__global__ __launch_bounds__(NTHREADS, 4) void ssim_fused(
    const float* __restrict__ x, const float* __restrict__ y,
    const float* __restrict__ win, float* __restrict__ partial)
{
    __shared__ __align__(16) f32x2 vab[TH][SAB];   // (mu_x, mu_y) pre-h: (x,y) vertical sums
    __shared__ __align__(16) f32x2 vqq[TH][SAB];   // (xx, yy) vertical sums
    __shared__ __align__(16) float vxy[TH][SXY];   // xy vertical sums
    __shared__ float sg[11];
    __shared__ float redbuf[5];

    const int tid = threadIdx.x;

    // 1D kernel g[i] = row sums of the 2D window (exact since sum(g)==1).
    if (tid < 11) {
        float s = 0.f;
        #pragma unroll
        for (int j = 0; j < 11; ++j) s += win[tid * 11 + j];
        sg[tid] = s;
    }

    const int x0 = blockIdx.x * TW;
    const int y0 = blockIdx.y * TH;
    const size_t img_off = (size_t)blockIdx.z * (IMG * IMG);
    const float* __restrict__ xb = x + img_off;
    const float* __restrict__ yb = y + img_off;

    // ---------------- Phase 1: vertical conv (global -> LDS) ----------------
    // Lane owns one stored column sc (image col = x0 + sc - 5), 8 output rows.
    const int s  = tid / 80;          // segment 0..3
    const int c  = tid - s * 80;      // stored col lane 0..79
    const int r0 = s * 8;             // first output row of segment
    const int gx = x0 + c - 5;        // global column
    const int cw = (c < 77) ? c : 77; // junk lanes (78,79) collide on pad col 77

    const bool cok = (gx >= 0) && (gx < IMG);
    f32x2 pab[18];
    #pragma unroll
    for (int j = 0; j < 18; ++j) {
        int gy = y0 + r0 - 5 + j;
        bool ok = cok && (gy >= 0) && (gy < IMG);
        int o = ok ? (gy * IMG + gx) : 0;
        float a = xb[o];
        float b = yb[o];
        pab[j][0] = ok ? a : 0.f;
        pab[j][1] = ok ? b : 0.f;
    }

    __syncthreads();   // sg visible
    f32x2 g2[11];
    #pragma unroll
    for (int k = 0; k < 11; ++k) { float gv = sg[k]; g2[k][0] = gv; g2[k][1] = gv; }

    // xy channel (scalar conv)
    {
        float t[18];
        #pragma unroll
        for (int j = 0; j < 18; ++j) t[j] = pab[j][0] * pab[j][1];
        #pragma unroll
        for (int i = 0; i < 8; ++i) {
            float a = 0.f;
            #pragma unroll
            for (int k = 0; k < 11; ++k) a = fmaf(g2[k][0], t[i + k], a);
            vxy[r0 + i][cw] = a;
        }
    }
    // (xx,yy) channel pair (packed)
    {
        f32x2 t[18];
        #pragma unroll
        for (int j = 0; j < 18; ++j) t[j] = pk_mul(pab[j], pab[j]);
        #pragma unroll
        for (int i = 0; i < 8; ++i) {
            f32x2 q = (f32x2)(0.f);
            #pragma unroll
            for (int k = 0; k < 11; ++k) q = pk_fma(g2[k], t[i + k], q);
            vqq[r0 + i][cw] = q;
        }
    }
    // (x,y) channel pair (packed)
    {
        #pragma unroll
        for (int i = 0; i < 8; ++i) {
            f32x2 a = (f32x2)(0.f);
            #pragma unroll
            for (int k = 0; k < 11; ++k) a = pk_fma(g2[k], pab[i + k], a);
            vab[r0 + i][cw] = a;
        }
    }

    __syncthreads();

    // ---------------- Phase 2: horizontal conv + SSIM ----------------
    const float C1 = 1.0e-4f;
    const float C2 = 9.0e-4f;
    float acc = 0.f;

    if (tid < 256) {
        const int rr = tid >> 3;          // row 0..31
        const int c0 = (tid & 7) * 8;     // output col base 0..56 (step 8)
        // out col c0+i taps stored cols (c0+i)..(c0+i+10); read cols c0..c0+17.

        f32x2 mu[8], qq[8];
        {
            f32x2 t[18];
            const float4* p = (const float4*)&vab[rr][c0];  // rr*624+64m bytes, 16B aligned
            #pragma unroll
            for (int q = 0; q < 9; ++q) {
                float4 f = p[q];
                t[2*q][0] = f.x;  t[2*q][1] = f.y;
                t[2*q+1][0] = f.z;  t[2*q+1][1] = f.w;
            }
            #pragma unroll
            for (int i = 0; i < 8; ++i) {
                f32x2 a = (f32x2)(0.f);
                #pragma unroll
                for (int k = 0; k < 11; ++k) a = pk_fma(g2[k], t[i + k], a);
                mu[i] = a;
            }
        }
        {
            f32x2 t[18];
            const float4* p = (const float4*)&vqq[rr][c0];
            #pragma unroll
            for (int q = 0; q < 9; ++q) {
                float4 f = p[q];
                t[2*q][0] = f.x;  t[2*q][1] = f.y;
                t[2*q+1][0] = f.z;  t[2*q+1][1] = f.w;
            }
            #pragma unroll
            for (int i = 0; i < 8; ++i) {
                f32x2 a = (f32x2)(0.f);
                #pragma unroll
                for (int k = 0; k < 11; ++k) a = pk_fma(g2[k], t[i + k], a);
                qq[i] = a;
            }
        }
        float exy[8];
        {
            float t[20];
            const float4* p = (const float4*)&vxy[rr][c0];  // rr*336+32m bytes, 16B aligned
            #pragma unroll
            for (int q = 0; q < 5; ++q) {
                float4 f = p[q];
                t[4*q + 0] = f.x; t[4*q + 1] = f.y; t[4*q + 2] = f.z; t[4*q + 3] = f.w;
            }
            #pragma unroll
            for (int i = 0; i < 8; ++i) {
                float a = 0.f;
                #pragma unroll
                for (int k = 0; k < 11; ++k) a = fmaf(g2[k][0], t[i + k], a);
                exy[i] = a;
            }
        }

        #pragma unroll
        for (int i = 0; i < 8; ++i) {
            f32x2 m2 = pk_mul(mu[i], mu[i]);        // (mxx, myy)
            float mxy = mu[i][0] * mu[i][1];
            float sxx = qq[i][0] - m2[0];
            float syy = qq[i][1] - m2[1];
            float sxy = exy[i] - mxy;
            float num = (2.f * mxy + C1) * (2.f * sxy + C2);
            float den = (m2[0] + m2[1] + C1) * (sxx + syy + C2);
            acc += num * __builtin_amdgcn_rcpf(den);
        }
    }

    // ---------------- Phase 3: block reduction ----------------
    #pragma unroll
    for (int off = 32; off > 0; off >>= 1) acc += __shfl_down(acc, off, 64);
    int wid = tid >> 6, lane = tid & 63;
    if (lane == 0) redbuf[wid] = acc;
    __syncthreads();
    if (tid == 0) {
        float ssum = redbuf[0] + redbuf[1] + redbuf[2] + redbuf[3] + redbuf[4];
        partial[((size_t)blockIdx.z * gridDim.y + blockIdx.y) * gridDim.x + blockIdx.x] = ssum;
    }
}

__global__ __launch_bounds__(256) void ssim_finalize(
    const float* __restrict__ partial, int n, float* __restrict__ out)
{
    __shared__ double red[4];
    double acc = 0.0;
    for (int i = threadIdx.x; i < n; i += 256) acc += (double)partial[i];
    #pragma unroll
    for (int off = 32; off > 0; off >>= 1) acc += __shfl_down(acc, off, 64);
    int wid = threadIdx.x >> 6, lane = threadIdx.x & 63;
    if (lane == 0) red[wid] = acc;
    __syncthreads();
    if (threadIdx.x == 0) {
        double s = red[0] + red[1] + red[2] + red[3];
        out[0] = (float)(s / (64.0 * 512.0 * 512.0));
    }
}

extern "C" void kernel_launch(void* const* d_in, const int* in_sizes, int n_in,
                              void* d_out, int out_size, void* d_ws, size_t ws_size,
                              hipStream_t stream) {
    (void)in_sizes; (void)n_in; (void)out_size; (void)ws_size;
    const float* x   = (const float*)d_in[0];
    const float* y   = (const float*)d_in[1];
    const float* win = (const float*)d_in[2];
    float* out = (float*)d_out;
    float* partial = (float*)d_ws;     // 8192 floats = 32 KB

    dim3 grid(IMG / TW, IMG / TH, 64); // 8 x 16 x 64 = 8192 blocks
    ssim_fused<<<grid, NTHREADS, 0, stream>>>(x, y, win, partial);
    ssim_finalize<<<1, 256, 0, stream>>>(partial, 8192, out);
}

// Round 6
// 181.597 us; speedup vs baseline: 1.4967x; 1.1767x over previous
//
#include <hip/hip_runtime.h>

// Fused SSIM, B=64, C=1, 512x512 fp32, 11x11 separable Gaussian.
// R6: (s,d) channel transform. s=x+y, d=x-y. SSIM needs only mxx+myy, mxy,
// sxx+syy, sxy, all recoverable from conv(s), conv(d), conv(s^2), conv(d^2):
//   ms^2+md^2 = 2(mxx+myy)    ms^2-md^2 = 4 mxy
//   E[ss]+E[dd] = 2(exx+eyy)  E[ss]-E[dd] = 4 exy
// => only TWO packed f32x2 conv channels: (s,d) and (ss,dd).
// Phase 1: vertical conv from global (per-lane column, 4x8-row segments).
// Phase 2: horizontal conv from LDS (aligned float4 runs) + SSIM + reduce.
// LDS = 2 planes * 32 * 78 * 8B = 39.9 KB -> 4 blocks/CU.

#define IMG 512
#define TW 64
#define TH 32
#define SAB 78           // f32x2 stride (156 words; 156%32=28 -> 8 spread start-banks)
#define NTHREADS 320

typedef __attribute__((ext_vector_type(2))) float f32x2;

static __device__ __forceinline__ f32x2 pk_fma(f32x2 a, f32x2 b, f32x2 c) {
    f32x2 d;
    asm("v_pk_fma_f32 %0, %1, %2, %3" : "=v"(d) : "v"(a), "v"(b), "v"(c));
    return d;
}
static __device__ __forceinline__ f32x2 pk_mul(f32x2 a, f32x2 b) {
    f32x2 d;
    asm("v_pk_mul_f32 %0, %1, %2" : "=v"(d) : "v"(a), "v"(b));
    return d;
}

__global__ __launch_bounds__(NTHREADS, 5) void ssim_fused(
    const float* __restrict__ x, const float* __restrict__ y,
    const float* __restrict__ win, float* __restrict__ partial)
{
    __shared__ __align__(16) f32x2 vab[TH][SAB];   // vertical conv of (s, d)
    __shared__ __align__(16) f32x2 vqq[TH][SAB];   // vertical conv of (s^2, d^2)
    __shared__ float sg[11];
    __shared__ float redbuf[5];

    const int tid = threadIdx.x;

    // 1D kernel g[i] = row sums of the 2D window (exact since sum(g)==1).
    if (tid < 11) {
        float s = 0.f;
        #pragma unroll
        for (int j = 0; j < 11; ++j) s += win[tid * 11 + j];
        sg[tid] = s;
    }

    const int x0 = blockIdx.x * TW;
    const int y0 = blockIdx.y * TH;
    const size_t img_off = (size_t)blockIdx.z * (IMG * IMG);
    const float* __restrict__ xb = x + img_off;
    const float* __restrict__ yb = y + img_off;

    // ---------------- Phase 1: vertical conv (global -> LDS) ----------------
    // Lane owns one stored column sc (image col = x0 + sc - 5), 8 output rows.
    const int sgm = tid / 80;          // segment 0..3
    const int c   = tid - sgm * 80;    // stored col lane 0..79
    const int r0  = sgm * 8;           // first output row of segment
    const int gx  = x0 + c - 5;        // global column
    const int cw  = (c < 76) ? c : 75; // junk lanes (76..79) park on pad col 75

    const bool cok = (gx >= 0) && (gx < IMG);
    f32x2 pab[18];                     // (s, d) per input row
    #pragma unroll
    for (int j = 0; j < 18; ++j) {
        int gy = y0 + r0 - 5 + j;
        bool ok = cok && (gy >= 0) && (gy < IMG);
        int o = ok ? (gy * IMG + gx) : 0;
        float a = xb[o];
        float b = yb[o];
        a = ok ? a : 0.f;
        b = ok ? b : 0.f;
        pab[j][0] = a + b;
        pab[j][1] = a - b;
    }

    __syncthreads();   // sg visible
    f32x2 g2[11];
    #pragma unroll
    for (int k = 0; k < 11; ++k) { float gv = sg[k]; g2[k][0] = gv; g2[k][1] = gv; }

    // (s^2, d^2) channel pair
    {
        f32x2 t[18];
        #pragma unroll
        for (int j = 0; j < 18; ++j) t[j] = pk_mul(pab[j], pab[j]);
        #pragma unroll
        for (int i = 0; i < 8; ++i) {
            f32x2 q = (f32x2)(0.f);
            #pragma unroll
            for (int k = 0; k < 11; ++k) q = pk_fma(g2[k], t[i + k], q);
            vqq[r0 + i][cw] = q;
        }
    }
    // (s, d) channel pair
    {
        #pragma unroll
        for (int i = 0; i < 8; ++i) {
            f32x2 a = (f32x2)(0.f);
            #pragma unroll
            for (int k = 0; k < 11; ++k) a = pk_fma(g2[k], pab[i + k], a);
            vab[r0 + i][cw] = a;
        }
    }

    __syncthreads();

    // ---------------- Phase 2: horizontal conv + SSIM ----------------
    const float C1 = 1.0e-4f;
    const float C2 = 9.0e-4f;
    float acc = 0.f;

    if (tid < 256) {
        const int rr = tid >> 3;          // row 0..31
        const int c0 = (tid & 7) * 8;     // output col base 0..56 (step 8)
        // out col c0+i taps stored cols (c0+i)..(c0+i+10); read cols c0..c0+17.

        f32x2 mu[8], qq[8];
        {
            f32x2 t[18];
            const float4* p = (const float4*)&vab[rr][c0];  // 16B aligned
            #pragma unroll
            for (int q = 0; q < 9; ++q) {
                float4 f = p[q];
                t[2*q][0] = f.x;  t[2*q][1] = f.y;
                t[2*q+1][0] = f.z;  t[2*q+1][1] = f.w;
            }
            #pragma unroll
            for (int i = 0; i < 8; ++i) {
                f32x2 a = (f32x2)(0.f);
                #pragma unroll
                for (int k = 0; k < 11; ++k) a = pk_fma(g2[k], t[i + k], a);
                mu[i] = a;
            }
        }
        {
            f32x2 t[18];
            const float4* p = (const float4*)&vqq[rr][c0];
            #pragma unroll
            for (int q = 0; q < 9; ++q) {
                float4 f = p[q];
                t[2*q][0] = f.x;  t[2*q][1] = f.y;
                t[2*q+1][0] = f.z;  t[2*q+1][1] = f.w;
            }
            #pragma unroll
            for (int i = 0; i < 8; ++i) {
                f32x2 a = (f32x2)(0.f);
                #pragma unroll
                for (int k = 0; k < 11; ++k) a = pk_fma(g2[k], t[i + k], a);
                qq[i] = a;
            }
        }

        #pragma unroll
        for (int i = 0; i < 8; ++i) {
            // mu[i] = (ms, md); qq[i] = (Ess, Edd)
            f32x2 m2 = pk_mul(mu[i], mu[i]);      // (ms^2, md^2)
            float P = m2[0] + m2[1];              // 2(mxx+myy)
            float Q = m2[0] - m2[1];              // 4 mxy
            float R = qq[i][0] + qq[i][1];        // 2(exx+eyy)
            float S = qq[i][0] - qq[i][1];        // 4 exy
            // num = (2 mxy + C1)(2 sxy + C2); 2 mxy = Q/2; 2 sxy = (S-Q)/2
            float num1 = fmaf(0.5f, Q, C1);
            float num2 = fmaf(0.5f, S - Q, C2);
            // den = (mxx+myy+C1)(sxx+syy+C2) = (P/2+C1)((R-P)/2+C2)
            float den1 = fmaf(0.5f, P, C1);
            float den2 = fmaf(0.5f, R - P, C2);
            acc += (num1 * num2) * __builtin_amdgcn_rcpf(den1 * den2);
        }
    }

    // ---------------- Phase 3: block reduction ----------------
    #pragma unroll
    for (int off = 32; off > 0; off >>= 1) acc += __shfl_down(acc, off, 64);
    int wid = tid >> 6, lane = tid & 63;
    if (lane == 0) redbuf[wid] = acc;
    __syncthreads();
    if (tid == 0) {
        float ssum = redbuf[0] + redbuf[1] + redbuf[2] + redbuf[3] + redbuf[4];
        partial[((size_t)blockIdx.z * gridDim.y + blockIdx.y) * gridDim.x + blockIdx.x] = ssum;
    }
}

#define NPART 8192

__global__ __launch_bounds__(1024) void ssim_finalize(
    const float* __restrict__ partial, float* __restrict__ out)
{
    __shared__ double red[16];
    double acc = 0.0;
    #pragma unroll
    for (int q = 0; q < NPART / 1024; ++q) acc += (double)partial[q * 1024 + threadIdx.x];
    #pragma unroll
    for (int off = 32; off > 0; off >>= 1) acc += __shfl_down(acc, off, 64);
    int wid = threadIdx.x >> 6, lane = threadIdx.x & 63;
    if (lane == 0) red[wid] = acc;
    __syncthreads();
    if (threadIdx.x == 0) {
        double ssum = 0.0;
        #pragma unroll
        for (int w = 0; w < 16; ++w) ssum += red[w];
        out[0] = (float)(ssum / (64.0 * 512.0 * 512.0));
    }
}

extern "C" void kernel_launch(void* const* d_in, const int* in_sizes, int n_in,
                              void* d_out, int out_size, void* d_ws, size_t ws_size,
                              hipStream_t stream) {
    (void)in_sizes; (void)n_in; (void)out_size; (void)ws_size;
    const float* x   = (const float*)d_in[0];
    const float* y   = (const float*)d_in[1];
    const float* win = (const float*)d_in[2];
    float* out = (float*)d_out;
    float* partial = (float*)d_ws;     // 8192 floats = 32 KB

    dim3 grid(IMG / TW, IMG / TH, 64); // 8 x 16 x 64 = 8192 blocks
    ssim_fused<<<grid, NTHREADS, 0, stream>>>(x, y, win, partial);
    ssim_finalize<<<1, 1024, 0, stream>>>(partial, out);
}

// Round 7
// 167.244 us; speedup vs baseline: 1.6251x; 1.0858x over previous
//
#include <hip/hip_runtime.h>

// Fused SSIM, B=64, C=1, 512x512 fp32, 11x11 separable Gaussian.
// R7: full-height band kernel. Block = 512-wide x 64-row band (grid 8 x 64
// images = 512 blocks = exactly 2 blocks/CU). Lane owns one image column and
// slides an 18-row (s,d) register window down the band: every input row is
// loaded ONCE (vs 2.25x in the segmented R6 phase 1), y-bounds are
// block-uniform scalar branches, x-bounds vanish via zero-padded LDS columns.
// Per 8-row chunk: load 8 rows -> v-conv (packed (s,d),(s2,d2)) -> LDS ->
// barrier -> h-conv + SSIM (R6's proven aligned-float4 shape, all 512 lanes
// active) -> barrier -> shift window.

#define IMG 512
#define BH 64            // band height (output rows per block)
#define CHUNK 8
#define NCHUNK (BH / CHUNK)
#define SROW 524         // f32x2 per row per plane: 5 pad + 512 + 5 pad + 2 align
#define NTHREADS 512

typedef __attribute__((ext_vector_type(2))) float f32x2;

static __device__ __forceinline__ f32x2 pk_fma(f32x2 a, f32x2 b, f32x2 c) {
    f32x2 d;
    asm("v_pk_fma_f32 %0, %1, %2, %3" : "=v"(d) : "v"(a), "v"(b), "v"(c));
    return d;
}
static __device__ __forceinline__ f32x2 pk_mul(f32x2 a, f32x2 b) {
    f32x2 d;
    asm("v_pk_mul_f32 %0, %1, %2" : "=v"(d) : "v"(a), "v"(b));
    return d;
}

__global__ __launch_bounds__(NTHREADS, 4) void ssim_band(
    const float* __restrict__ x, const float* __restrict__ y,
    const float* __restrict__ win, float* __restrict__ partial)
{
    __shared__ __align__(16) f32x2 vab[CHUNK][SROW];   // v-conv of (s, d)
    __shared__ __align__(16) f32x2 vqq[CHUNK][SROW];   // v-conv of (s^2, d^2)
    __shared__ float sg[11];
    __shared__ float redbuf[NTHREADS / 64];

    const int tid = threadIdx.x;

    // 1D kernel g[i] = row sums of the 2D window (exact since sum(g)==1).
    if (tid < 11) {
        float s = 0.f;
        #pragma unroll
        for (int j = 0; j < 11; ++j) s += win[tid * 11 + j];
        sg[tid] = s;
    }
    // Zero the pad columns once (LDS is re-poisoned every launch).
    // 2 planes * 8 rows * 10 pad cols = 160 entries.
    if (tid < 160) {
        int plane = tid / 80, rem = tid % 80, row = rem / 10, pc = rem % 10;
        int cc = (pc < 5) ? pc : (512 + pc);   // stored cols 0..4, 517..521
        f32x2 z = (f32x2)(0.f);
        if (plane == 0) vab[row][cc] = z; else vqq[row][cc] = z;
    }

    const int y0 = blockIdx.x * BH;
    const size_t img_off = (size_t)blockIdx.y * (IMG * IMG);
    const float* __restrict__ xb = x + img_off + tid;   // lane-column base
    const float* __restrict__ yb = y + img_off + tid;

    // Prologue: input rows y0-5 .. y0+4 -> pab[0..9]. gy is block-uniform ->
    // the bounds check is a scalar branch, no per-lane mask code.
    f32x2 pab[18];
    #pragma unroll
    for (int j = 0; j < 10; ++j) {
        int gy = y0 - 5 + j;
        float a = 0.f, b = 0.f;
        if (gy >= 0) { a = xb[gy * IMG]; b = yb[gy * IMG]; }
        pab[j][0] = a + b;
        pab[j][1] = a - b;
    }

    __syncthreads();   // sg + pad zeros visible
    f32x2 g2[11];
    #pragma unroll
    for (int k = 0; k < 11; ++k) { float gv = sg[k]; g2[k][0] = gv; g2[k][1] = gv; }

    const float C1 = 1.0e-4f;
    const float C2 = 9.0e-4f;
    float acc = 0.f;

    const int rr = tid >> 6;          // h-conv: row 0..7 of chunk
    const int c0 = (tid & 63) * 8;    // h-conv: output col base (even -> 16B aligned)

    for (int k = 0; k < NCHUNK; ++k) {
        const int r0 = y0 + k * CHUNK;

        // Load 8 new input rows r0+5 .. r0+12 -> pab[10..17].
        #pragma unroll
        for (int j = 0; j < 8; ++j) {
            int gy = r0 + 5 + j;      // block-uniform
            float a = 0.f, b = 0.f;
            if (gy < IMG) { a = xb[gy * IMG]; b = yb[gy * IMG]; }
            pab[10 + j][0] = a + b;
            pab[10 + j][1] = a - b;
        }

        // Squares of the 18-row window.
        f32x2 sq[18];
        #pragma unroll
        for (int j = 0; j < 18; ++j) sq[j] = pk_mul(pab[j], pab[j]);

        // Vertical conv: 8 output rows -> LDS (stored col = image col + 5).
        #pragma unroll
        for (int i = 0; i < CHUNK; ++i) {
            f32x2 a = (f32x2)(0.f), q = (f32x2)(0.f);
            #pragma unroll
            for (int t = 0; t < 11; ++t) {
                a = pk_fma(g2[t], pab[i + t], a);
                q = pk_fma(g2[t], sq[i + t], q);
            }
            vab[i][tid + 5] = a;
            vqq[i][tid + 5] = q;
        }

        __syncthreads();

        // Horizontal conv + SSIM: 8 outputs per lane (row rr, cols c0..c0+7).
        // Out col c taps stored cols c..c+10; lane reads stored c0..c0+17.
        {
            f32x2 mu[8], qq[8];
            {
                f32x2 t[18];
                const float4* p = (const float4*)&vab[rr][c0];
                #pragma unroll
                for (int q8 = 0; q8 < 9; ++q8) {
                    float4 f = p[q8];
                    t[2*q8][0] = f.x;  t[2*q8][1] = f.y;
                    t[2*q8+1][0] = f.z;  t[2*q8+1][1] = f.w;
                }
                #pragma unroll
                for (int i = 0; i < 8; ++i) {
                    f32x2 a = (f32x2)(0.f);
                    #pragma unroll
                    for (int t1 = 0; t1 < 11; ++t1) a = pk_fma(g2[t1], t[i + t1], a);
                    mu[i] = a;
                }
            }
            {
                f32x2 t[18];
                const float4* p = (const float4*)&vqq[rr][c0];
                #pragma unroll
                for (int q8 = 0; q8 < 9; ++q8) {
                    float4 f = p[q8];
                    t[2*q8][0] = f.x;  t[2*q8][1] = f.y;
                    t[2*q8+1][0] = f.z;  t[2*q8+1][1] = f.w;
                }
                #pragma unroll
                for (int i = 0; i < 8; ++i) {
                    f32x2 a = (f32x2)(0.f);
                    #pragma unroll
                    for (int t1 = 0; t1 < 11; ++t1) a = pk_fma(g2[t1], t[i + t1], a);
                    qq[i] = a;
                }
            }

            #pragma unroll
            for (int i = 0; i < 8; ++i) {
                // mu[i] = (ms, md); qq[i] = (Ess, Edd)
                f32x2 m2 = pk_mul(mu[i], mu[i]);      // (ms^2, md^2)
                float P = m2[0] + m2[1];              // 2(mxx+myy)
                float Q = m2[0] - m2[1];              // 4 mxy
                float R = qq[i][0] + qq[i][1];        // 2(exx+eyy)
                float S = qq[i][0] - qq[i][1];        // 4 exy
                float num1 = fmaf(0.5f, Q, C1);
                float num2 = fmaf(0.5f, S - Q, C2);
                float den1 = fmaf(0.5f, P, C1);
                float den2 = fmaf(0.5f, R - P, C2);
                acc += (num1 * num2) * __builtin_amdgcn_rcpf(den1 * den2);
            }
        }

        __syncthreads();

        // Slide window down by 8 rows.
        #pragma unroll
        for (int j = 0; j < 10; ++j) pab[j] = pab[j + 8];
    }

    // Block reduction.
    #pragma unroll
    for (int off = 32; off > 0; off >>= 1) acc += __shfl_down(acc, off, 64);
    int wid = tid >> 6, lane = tid & 63;
    if (lane == 0) redbuf[wid] = acc;
    __syncthreads();
    if (tid == 0) {
        float ssum = 0.f;
        #pragma unroll
        for (int w = 0; w < NTHREADS / 64; ++w) ssum += redbuf[w];
        partial[blockIdx.y * gridDim.x + blockIdx.x] = ssum;
    }
}

#define NPART 512

__global__ __launch_bounds__(512) void ssim_finalize(
    const float* __restrict__ partial, float* __restrict__ out)
{
    __shared__ double red[8];
    double acc = (double)partial[threadIdx.x];
    #pragma unroll
    for (int off = 32; off > 0; off >>= 1) acc += __shfl_down(acc, off, 64);
    int wid = threadIdx.x >> 6, lane = threadIdx.x & 63;
    if (lane == 0) red[wid] = acc;
    __syncthreads();
    if (threadIdx.x == 0) {
        double ssum = 0.0;
        #pragma unroll
        for (int w = 0; w < 8; ++w) ssum += red[w];
        out[0] = (float)(ssum / (64.0 * 512.0 * 512.0));
    }
}

extern "C" void kernel_launch(void* const* d_in, const int* in_sizes, int n_in,
                              void* d_out, int out_size, void* d_ws, size_t ws_size,
                              hipStream_t stream) {
    (void)in_sizes; (void)n_in; (void)out_size; (void)ws_size;
    const float* x   = (const float*)d_in[0];
    const float* y   = (const float*)d_in[1];
    const float* win = (const float*)d_in[2];
    float* out = (float*)d_out;
    float* partial = (float*)d_ws;     // 512 floats

    dim3 grid(IMG / BH, 64);           // 8 x 64 = 512 blocks, 2 per CU
    ssim_band<<<grid, NTHREADS, 0, stream>>>(x, y, win, partial);
    ssim_finalize<<<1, NPART, 0, stream>>>(partial, out);
}

// Round 8
// 163.453 us; speedup vs baseline: 1.6628x; 1.0232x over previous
//
#include <hip/hip_runtime.h>

// Fused SSIM, B=64, C=1, 512x512 fp32, 11x11 separable Gaussian.
// R8 = R7 band kernel + h-conv bank-conflict fix.
// Block = 512-wide x 64-row band (grid 8 x 64 = 512 blocks = 2/CU). Lane owns
// one image column; slides an 18-row (s,d) register window; every input row
// loaded once. Per 8-row chunk: v-conv (packed) -> LDS -> barrier -> h-conv +
// SSIM -> barrier -> shift.
// Bank fix: h-conv lane mapping rr = tid&7 (row varies WITHIN the wave),
// c0 = (tid>>3)*8; row stride 522 f32x2 = 1044 words = 20 mod 32 -> start
// banks {20*rr} xor {0,16} = 8 distinct, closed under +16, 8 lanes each ->
// all 32 banks balanced (the R6-verified zero-conflict class).

#define IMG 512
#define BH 64            // band height (output rows per block)
#define CHUNK 8
#define NCHUNK (BH / CHUNK)
#define SROW 522         // f32x2 per row per plane: 5 pad + 512 + 5 pad
#define NTHREADS 512

typedef __attribute__((ext_vector_type(2))) float f32x2;

static __device__ __forceinline__ f32x2 pk_fma(f32x2 a, f32x2 b, f32x2 c) {
    f32x2 d;
    asm("v_pk_fma_f32 %0, %1, %2, %3" : "=v"(d) : "v"(a), "v"(b), "v"(c));
    return d;
}
static __device__ __forceinline__ f32x2 pk_mul(f32x2 a, f32x2 b) {
    f32x2 d;
    asm("v_pk_mul_f32 %0, %1, %2" : "=v"(d) : "v"(a), "v"(b));
    return d;
}

__global__ __launch_bounds__(NTHREADS, 4) void ssim_band(
    const float* __restrict__ x, const float* __restrict__ y,
    const float* __restrict__ win, float* __restrict__ partial)
{
    __shared__ __align__(16) f32x2 vab[CHUNK][SROW];   // v-conv of (s, d)
    __shared__ __align__(16) f32x2 vqq[CHUNK][SROW];   // v-conv of (s^2, d^2)
    __shared__ float sg[11];
    __shared__ float redbuf[NTHREADS / 64];

    const int tid = threadIdx.x;

    // 1D kernel g[i] = row sums of the 2D window (exact since sum(g)==1).
    if (tid < 11) {
        float s = 0.f;
        #pragma unroll
        for (int j = 0; j < 11; ++j) s += win[tid * 11 + j];
        sg[tid] = s;
    }
    // Zero the pad columns once (LDS is re-poisoned every launch).
    // 2 planes * 8 rows * 10 pad cols = 160 entries.
    if (tid < 160) {
        int plane = tid / 80, rem = tid % 80, row = rem / 10, pc = rem % 10;
        int cc = (pc < 5) ? pc : (512 + pc);   // stored cols 0..4, 517..521
        f32x2 z = (f32x2)(0.f);
        if (plane == 0) vab[row][cc] = z; else vqq[row][cc] = z;
    }

    const int y0 = blockIdx.x * BH;
    const size_t img_off = (size_t)blockIdx.y * (IMG * IMG);
    const float* __restrict__ xb = x + img_off + tid;   // lane-column base
    const float* __restrict__ yb = y + img_off + tid;

    // Prologue: input rows y0-5 .. y0+4 -> pab[0..9]. gy is block-uniform ->
    // the bounds check is a scalar branch, no per-lane mask code.
    f32x2 pab[18];
    #pragma unroll
    for (int j = 0; j < 10; ++j) {
        int gy = y0 - 5 + j;
        float a = 0.f, b = 0.f;
        if (gy >= 0) { a = xb[gy * IMG]; b = yb[gy * IMG]; }
        pab[j][0] = a + b;
        pab[j][1] = a - b;
    }

    __syncthreads();   // sg + pad zeros visible
    f32x2 g2[11];
    #pragma unroll
    for (int k = 0; k < 11; ++k) { float gv = sg[k]; g2[k][0] = gv; g2[k][1] = gv; }

    const float C1 = 1.0e-4f;
    const float C2 = 9.0e-4f;
    float acc = 0.f;

    const int rr = tid & 7;            // h-conv row: varies within the wave
    const int c0 = (tid >> 3) * 8;     // h-conv output col base (16B aligned)

    for (int k = 0; k < NCHUNK; ++k) {
        const int r0 = y0 + k * CHUNK;

        // Load 8 new input rows r0+5 .. r0+12 -> pab[10..17].
        #pragma unroll
        for (int j = 0; j < 8; ++j) {
            int gy = r0 + 5 + j;      // block-uniform
            float a = 0.f, b = 0.f;
            if (gy < IMG) { a = xb[gy * IMG]; b = yb[gy * IMG]; }
            pab[10 + j][0] = a + b;
            pab[10 + j][1] = a - b;
        }

        // Squares of the 18-row window.
        f32x2 sq[18];
        #pragma unroll
        for (int j = 0; j < 18; ++j) sq[j] = pk_mul(pab[j], pab[j]);

        // Vertical conv: 8 output rows -> LDS (stored col = image col + 5).
        #pragma unroll
        for (int i = 0; i < CHUNK; ++i) {
            f32x2 a = (f32x2)(0.f), q = (f32x2)(0.f);
            #pragma unroll
            for (int t = 0; t < 11; ++t) {
                a = pk_fma(g2[t], pab[i + t], a);
                q = pk_fma(g2[t], sq[i + t], q);
            }
            vab[i][tid + 5] = a;
            vqq[i][tid + 5] = q;
        }

        __syncthreads();

        // Horizontal conv + SSIM: 8 outputs per lane (row rr, cols c0..c0+7).
        // Out col c taps stored cols c..c+10; lane reads stored c0..c0+17.
        {
            f32x2 mu[8], qq[8];
            {
                f32x2 t[18];
                const float4* p = (const float4*)&vab[rr][c0];
                #pragma unroll
                for (int q8 = 0; q8 < 9; ++q8) {
                    float4 f = p[q8];
                    t[2*q8][0] = f.x;  t[2*q8][1] = f.y;
                    t[2*q8+1][0] = f.z;  t[2*q8+1][1] = f.w;
                }
                #pragma unroll
                for (int i = 0; i < 8; ++i) {
                    f32x2 a = (f32x2)(0.f);
                    #pragma unroll
                    for (int t1 = 0; t1 < 11; ++t1) a = pk_fma(g2[t1], t[i + t1], a);
                    mu[i] = a;
                }
            }
            {
                f32x2 t[18];
                const float4* p = (const float4*)&vqq[rr][c0];
                #pragma unroll
                for (int q8 = 0; q8 < 9; ++q8) {
                    float4 f = p[q8];
                    t[2*q8][0] = f.x;  t[2*q8][1] = f.y;
                    t[2*q8+1][0] = f.z;  t[2*q8+1][1] = f.w;
                }
                #pragma unroll
                for (int i = 0; i < 8; ++i) {
                    f32x2 a = (f32x2)(0.f);
                    #pragma unroll
                    for (int t1 = 0; t1 < 11; ++t1) a = pk_fma(g2[t1], t[i + t1], a);
                    qq[i] = a;
                }
            }

            #pragma unroll
            for (int i = 0; i < 8; ++i) {
                // mu[i] = (ms, md); qq[i] = (Ess, Edd)
                f32x2 m2 = pk_mul(mu[i], mu[i]);      // (ms^2, md^2)
                float P = m2[0] + m2[1];              // 2(mxx+myy)
                float Q = m2[0] - m2[1];              // 4 mxy
                float R = qq[i][0] + qq[i][1];        // 2(exx+eyy)
                float S = qq[i][0] - qq[i][1];        // 4 exy
                float num1 = fmaf(0.5f, Q, C1);
                float num2 = fmaf(0.5f, S - Q, C2);
                float den1 = fmaf(0.5f, P, C1);
                float den2 = fmaf(0.5f, R - P, C2);
                acc += (num1 * num2) * __builtin_amdgcn_rcpf(den1 * den2);
            }
        }

        __syncthreads();

        // Slide window down by 8 rows.
        #pragma unroll
        for (int j = 0; j < 10; ++j) pab[j] = pab[j + 8];
    }

    // Block reduction.
    #pragma unroll
    for (int off = 32; off > 0; off >>= 1) acc += __shfl_down(acc, off, 64);
    int wid = tid >> 6, lane = tid & 63;
    if (lane == 0) redbuf[wid] = acc;
    __syncthreads();
    if (tid == 0) {
        float ssum = 0.f;
        #pragma unroll
        for (int w = 0; w < NTHREADS / 64; ++w) ssum += redbuf[w];
        partial[blockIdx.y * gridDim.x + blockIdx.x] = ssum;
    }
}

#define NPART 512

__global__ __launch_bounds__(512) void ssim_finalize(
    const float* __restrict__ partial, float* __restrict__ out)
{
    __shared__ double red[8];
    double acc = (double)partial[threadIdx.x];
    #pragma unroll
    for (int off = 32; off > 0; off >>= 1) acc += __shfl_down(acc, off, 64);
    int wid = threadIdx.x >> 6, lane = threadIdx.x & 63;
    if (lane == 0) red[wid] = acc;
    __syncthreads();
    if (threadIdx.x == 0) {
        double ssum = 0.0;
        #pragma unroll
        for (int w = 0; w < 8; ++w) ssum += red[w];
        out[0] = (float)(ssum / (64.0 * 512.0 * 512.0));
    }
}

extern "C" void kernel_launch(void* const* d_in, const int* in_sizes, int n_in,
                              void* d_out, int out_size, void* d_ws, size_t ws_size,
                              hipStream_t stream) {
    (void)in_sizes; (void)n_in; (void)out_size; (void)ws_size;
    const float* x   = (const float*)d_in[0];
    const float* y   = (const float*)d_in[1];
    const float* win = (const float*)d_in[2];
    float* out = (float*)d_out;
    float* partial = (float*)d_ws;     // 512 floats

    dim3 grid(IMG / BH, 64);           // 8 x 64 = 512 blocks, 2 per CU
    ssim_band<<<grid, NTHREADS, 0, stream>>>(x, y, win, partial);
    ssim_finalize<<<1, NPART, 0, stream>>>(partial, out);
}